// Round 3
// baseline (1932.975 us; speedup 1.0000x reference)
//
#include <hip/hip_runtime.h>

#define SEPS 1e-10f

__device__ __forceinline__ float fast_rcp(float x) { return __builtin_amdgcn_rcpf(x); }
__device__ __forceinline__ float fast_exp(float x) { return __expf(x); }
__device__ __forceinline__ float fast_sigmoid(float x) {
    return fast_rcp(1.0f + fast_exp(-x));
}

// 2 rows per thread, fully unrolled (every array index compile-time).
// __launch_bounds__(256,1): max VGPR budget -> discourage the allocator from
// keeping arch-VGPRs tiny and shuttling accumulators through AGPRs
// (v_accvgpr_read/write), which inflated VALU issue 3x in the previous round.
__global__ __launch_bounds__(256, 1) void sinkhorn_mlp_kernel(
    const float* __restrict__ margins,
    const float* __restrict__ W1, const float* __restrict__ b1,
    const float* __restrict__ W2, const float* __restrict__ b2,
    const float* __restrict__ W3, const float* __restrict__ b3,
    const float* __restrict__ W4, const float* __restrict__ b4,
    float* __restrict__ out_mus, float* __restrict__ out_V, int n)
{
    const int lane = threadIdx.x;
    const size_t base = (size_t)blockIdx.x * 512;

    size_t r[2] = { base + lane, base + 256 + lane };
    bool ok[2] = { r[0] < (size_t)n, r[1] < (size_t)n };
    size_t rc[2] = { ok[0] ? r[0] : 0, ok[1] ? r[1] : 0 };

    // ---- load margins (6 floats/row, 8B-aligned) ----
    float m[2][6];
#pragma unroll
    for (int rr = 0; rr < 2; ++rr) {
        const float2* mp = reinterpret_cast<const float2*>(margins + rc[rr] * 6);
        float2 a = mp[0], b = mp[1], c = mp[2];
        m[rr][0] = a.x; m[rr][1] = a.y; m[rr][2] = b.x;
        m[rr][3] = b.y; m[rr][4] = c.x; m[rr][5] = c.y;
    }

    // ---- layers 1+2 fused, both rows interleaved ----
    float h2[2][32];
#pragma unroll
    for (int j = 0; j < 32; ++j) { float bb = b2[j]; h2[0][j] = bb; h2[1][j] = bb; }

#pragma unroll
    for (int k = 0; k < 64; ++k) {
        float bk = b1[k];
        float t0 = bk, t1 = bk;
#pragma unroll
        for (int i = 0; i < 6; ++i) {
            float w = W1[i * 64 + k];
            t0 = fmaf(m[0][i], w, t0);
            t1 = fmaf(m[1][i], w, t1);
        }
        t0 = fmaxf(t0, 0.0f);
        t1 = fmaxf(t1, 0.0f);
#pragma unroll
        for (int j = 0; j < 32; ++j) {
            float w = W2[k * 32 + j];
            h2[0][j] = fmaf(t0, w, h2[0][j]);
            h2[1][j] = fmaf(t1, w, h2[1][j]);
        }
    }

    // ---- layer 3 fused ----
    float h3[2][16];
#pragma unroll
    for (int j = 0; j < 16; ++j) { float bb = b3[j]; h3[0][j] = bb; h3[1][j] = bb; }
#pragma unroll
    for (int k = 0; k < 32; ++k) {
        float t0 = fmaxf(h2[0][k], 0.0f);
        float t1 = fmaxf(h2[1][k], 0.0f);
#pragma unroll
        for (int j = 0; j < 16; ++j) {
            float w = W3[k * 16 + j];
            h3[0][j] = fmaf(t0, w, h3[0][j]);
            h3[1][j] = fmaf(t1, w, h3[1][j]);
        }
    }

    // ---- layer 4 fused ----
    float pars[2][9];
#pragma unroll
    for (int j = 0; j < 9; ++j) { float bb = b4[j]; pars[0][j] = bb; pars[1][j] = bb; }
#pragma unroll
    for (int k = 0; k < 16; ++k) {
        float t0 = fmaxf(h3[0][k], 0.0f);
        float t1 = fmaxf(h3[1][k], 0.0f);
#pragma unroll
        for (int j = 0; j < 9; ++j) {
            float w = W4[k * 9 + j];
            pars[0][j] = fmaf(t0, w, pars[0][j]);
            pars[1][j] = fmaf(t1, w, pars[1][j]);
        }
    }

    // ---- heads + Sinkhorn + store, per row ----
#pragma unroll
    for (int rr = 0; rr < 2; ++rr) {
        float p0 = fast_exp(pars[rr][0]);
        float p1 = fast_exp(pars[rr][1]);
        float p2 = fast_exp(pars[rr][2]);
        float p3 = fast_exp(pars[rr][3]);

        float A00 = p3 * p0, A01 = p3 * p1, A02 = p3 * p2;
        float A10 = p3 * p1, A11 = p3 * p0, A12 = p3 * p1;
        float A20 = p3 * p2, A21 = p3 * p1, A22 = p3 * p0;

        float sm0 = fast_sigmoid(pars[rr][4]);
        float sm1 = fast_sigmoid(pars[rr][5]);
        float sf0 = fast_sigmoid(pars[rr][6]);
        float sf1 = fast_sigmoid(pars[rr][7]);
        float V   = fast_exp(pars[rr][8]);

        float M0 = m[rr][0], M1 = m[rr][1], M2 = m[rr][2];
        float F0 = m[rr][3], F1 = m[rr][4], F2 = m[rr][5];

        float rc0 = M0 * sm0, rc1 = M1 * sm1, rc2 = M2;
        float cc0 = F0 * sf0, cc1 = F1 * sf1, cc2 = F2;
        float mum0_0 = M0 * (1.0f - sm0);
        float mum0_1 = M1 * (1.0f - sm1);
        float mu0f_0 = F0 * (1.0f - sf0);
        float mu0f_1 = F1 * (1.0f - sf1);

#pragma unroll
        for (int it = 0; it < 10; ++it) {
            float f0 = rc0 * fast_rcp(A00 + A01 + A02 + SEPS);
            float f1 = rc1 * fast_rcp(A10 + A11 + A12 + SEPS);
            float f2 = rc2 * fast_rcp(A20 + A21 + A22 + SEPS);
            A00 *= f0; A01 *= f0; A02 *= f0;
            A10 *= f1; A11 *= f1; A12 *= f1;
            A20 *= f2; A21 *= f2; A22 *= f2;
            float g0 = cc0 * fast_rcp(A00 + A10 + A20 + SEPS);
            float g1 = cc1 * fast_rcp(A01 + A11 + A21 + SEPS);
            float g2 = cc2 * fast_rcp(A02 + A12 + A22 + SEPS);
            A00 *= g0; A10 *= g0; A20 *= g0;
            A01 *= g1; A11 *= g1; A21 *= g1;
            A02 *= g2; A12 *= g2; A22 *= g2;
        }

        if (ok[rr]) {
            float4* o = reinterpret_cast<float4*>(out_mus + r[rr] * 16);
            o[0] = make_float4(A00, A01, A02, mum0_0);
            o[1] = make_float4(A10, A11, A12, mum0_1);
            o[2] = make_float4(A20, A21, A22, 0.0f);
            o[3] = make_float4(mu0f_0, mu0f_1, 0.0f, 0.0f);
            out_V[r[rr]] = V;
        }
    }
}

extern "C" void kernel_launch(void* const* d_in, const int* in_sizes, int n_in,
                              void* d_out, int out_size, void* d_ws, size_t ws_size,
                              hipStream_t stream) {
    const float* margins = (const float*)d_in[0];
    const float* W1 = (const float*)d_in[1];
    const float* b1 = (const float*)d_in[2];
    const float* W2 = (const float*)d_in[3];
    const float* b2 = (const float*)d_in[4];
    const float* W3 = (const float*)d_in[5];
    const float* b3 = (const float*)d_in[6];
    const float* W4 = (const float*)d_in[7];
    const float* b4 = (const float*)d_in[8];

    int n = in_sizes[0] / 6;
    float* out_mus = (float*)d_out;
    float* out_V   = out_mus + (size_t)n * 16;

    dim3 block(256);
    dim3 grid((n + 511) / 512);   // 2 rows per thread
    sinkhorn_mlp_kernel<<<grid, block, 0, stream>>>(
        margins, W1, b1, W2, b2, W3, b3, W4, b4, out_mus, out_V, n);
}

// Round 4
// 333.643 us; speedup vs baseline: 5.7935x; 5.7935x over previous
//
#include <hip/hip_runtime.h>

#define SEPS 1e-10f

__device__ __forceinline__ float fast_rcp(float x) { return __builtin_amdgcn_rcpf(x); }
__device__ __forceinline__ float fast_exp(float x) { return __expf(x); }
__device__ __forceinline__ float fast_sigmoid(float x) {
    return fast_rcp(1.0f + fast_exp(-x));
}

// 1 row/thread, fused accumulation, fully unrolled (all indices compile-time).
// amdgpu_waves_per_eu(4,4): declares the occupancy target exactly ->
//  - VGPR cap 512/4 = 128 (live state ~55 fits with no spill)
//  - no incentive for the allocator to squeeze arch-VGPRs below need and
//    shuttle accumulators through AGPRs (round-2 pathology, VGPR_Count=32)
//  - 4 waves/SIMD hides scalar-cache weight-load latency (round-3 pathology
//    was 1 wave/SIMD -> 2015us)
__global__ __launch_bounds__(256)
__attribute__((amdgpu_waves_per_eu(4, 4)))
void sinkhorn_mlp_kernel(
    const float* __restrict__ margins,
    const float* __restrict__ W1, const float* __restrict__ b1,
    const float* __restrict__ W2, const float* __restrict__ b2,
    const float* __restrict__ W3, const float* __restrict__ b3,
    const float* __restrict__ W4, const float* __restrict__ b4,
    float* __restrict__ out_mus, float* __restrict__ out_V, int n)
{
    int r = blockIdx.x * blockDim.x + threadIdx.x;
    if (r >= n) return;

    // ---- load margins (6 floats, 8B-aligned) ----
    const float2* mp = reinterpret_cast<const float2*>(margins + (size_t)r * 6);
    float2 mv0 = mp[0], mv1 = mp[1], mv2 = mp[2];
    float m0 = mv0.x, m1 = mv0.y, m2 = mv1.x, m3 = mv1.y, m4 = mv2.x, m5 = mv2.y;

    // ---- layers 1+2 fused: h2[j] = b2[j] + sum_k relu(h1_k) * W2[k][j] ----
    float h2[32];
#pragma unroll
    for (int j = 0; j < 32; ++j) h2[j] = b2[j];

#pragma unroll
    for (int k = 0; k < 64; ++k) {
        float t = b1[k];
        t = fmaf(m0, W1[0 * 64 + k], t);
        t = fmaf(m1, W1[1 * 64 + k], t);
        t = fmaf(m2, W1[2 * 64 + k], t);
        t = fmaf(m3, W1[3 * 64 + k], t);
        t = fmaf(m4, W1[4 * 64 + k], t);
        t = fmaf(m5, W1[5 * 64 + k], t);
        t = fmaxf(t, 0.0f);
#pragma unroll
        for (int j = 0; j < 32; ++j) h2[j] = fmaf(t, W2[k * 32 + j], h2[j]);
    }

    // ---- layer 3 fused ----
    float h3[16];
#pragma unroll
    for (int j = 0; j < 16; ++j) h3[j] = b3[j];
#pragma unroll
    for (int k = 0; k < 32; ++k) {
        float t = fmaxf(h2[k], 0.0f);
#pragma unroll
        for (int j = 0; j < 16; ++j) h3[j] = fmaf(t, W3[k * 16 + j], h3[j]);
    }

    // ---- layer 4 fused ----
    float pars[9];
#pragma unroll
    for (int j = 0; j < 9; ++j) pars[j] = b4[j];
#pragma unroll
    for (int k = 0; k < 16; ++k) {
        float t = fmaxf(h3[k], 0.0f);
#pragma unroll
        for (int j = 0; j < 9; ++j) pars[j] = fmaf(t, W4[k * 9 + j], pars[j]);
    }

    // ---- heads ----
    float p0 = fast_exp(pars[0]);
    float p1 = fast_exp(pars[1]);
    float p2 = fast_exp(pars[2]);
    float p3 = fast_exp(pars[3]);

    float A00 = p3 * p0, A01 = p3 * p1, A02 = p3 * p2;
    float A10 = p3 * p1, A11 = p3 * p0, A12 = p3 * p1;
    float A20 = p3 * p2, A21 = p3 * p1, A22 = p3 * p0;

    float sm0 = fast_sigmoid(pars[4]);
    float sm1 = fast_sigmoid(pars[5]);
    float sf0 = fast_sigmoid(pars[6]);
    float sf1 = fast_sigmoid(pars[7]);
    float V   = fast_exp(pars[8]);

    float rc0 = m0 * sm0, rc1 = m1 * sm1, rc2 = m2;   // row targets
    float cc0 = m3 * sf0, cc1 = m4 * sf1, cc2 = m5;   // col targets
    float mum0_0 = m0 * (1.0f - sm0);
    float mum0_1 = m1 * (1.0f - sm1);
    float mu0f_0 = m3 * (1.0f - sf0);
    float mu0f_1 = m4 * (1.0f - sf1);

    // ---- Sinkhorn: 10 iterations ----
#pragma unroll
    for (int it = 0; it < 10; ++it) {
        float f0 = rc0 * fast_rcp(A00 + A01 + A02 + SEPS);
        float f1 = rc1 * fast_rcp(A10 + A11 + A12 + SEPS);
        float f2 = rc2 * fast_rcp(A20 + A21 + A22 + SEPS);
        A00 *= f0; A01 *= f0; A02 *= f0;
        A10 *= f1; A11 *= f1; A12 *= f1;
        A20 *= f2; A21 *= f2; A22 *= f2;
        float g0 = cc0 * fast_rcp(A00 + A10 + A20 + SEPS);
        float g1 = cc1 * fast_rcp(A01 + A11 + A21 + SEPS);
        float g2 = cc2 * fast_rcp(A02 + A12 + A22 + SEPS);
        A00 *= g0; A10 *= g0; A20 *= g0;
        A01 *= g1; A11 *= g1; A21 *= g1;
        A02 *= g2; A12 *= g2; A22 *= g2;
    }

    // ---- output: mus (4x4 row-major) then V ----
    float4* o = reinterpret_cast<float4*>(out_mus + (size_t)r * 16);
    o[0] = make_float4(A00, A01, A02, mum0_0);
    o[1] = make_float4(A10, A11, A12, mum0_1);
    o[2] = make_float4(A20, A21, A22, 0.0f);
    o[3] = make_float4(mu0f_0, mu0f_1, 0.0f, 0.0f);
    out_V[r] = V;
}

extern "C" void kernel_launch(void* const* d_in, const int* in_sizes, int n_in,
                              void* d_out, int out_size, void* d_ws, size_t ws_size,
                              hipStream_t stream) {
    const float* margins = (const float*)d_in[0];
    const float* W1 = (const float*)d_in[1];
    const float* b1 = (const float*)d_in[2];
    const float* W2 = (const float*)d_in[3];
    const float* b2 = (const float*)d_in[4];
    const float* W3 = (const float*)d_in[5];
    const float* b3 = (const float*)d_in[6];
    const float* W4 = (const float*)d_in[7];
    const float* b4 = (const float*)d_in[8];

    int n = in_sizes[0] / 6;
    float* out_mus = (float*)d_out;
    float* out_V   = out_mus + (size_t)n * 16;

    dim3 block(256);
    dim3 grid((n + 255) / 256);
    sinkhorn_mlp_kernel<<<grid, block, 0, stream>>>(
        margins, W1, b1, W2, b2, W3, b3, W4, b4, out_mus, out_V, n);
}

// Round 7
// 171.370 us; speedup vs baseline: 11.2795x; 1.9469x over previous
//
#include <hip/hip_runtime.h>

#define SEPS 1e-10f

__device__ __forceinline__ float fast_rcp(float x) { return __builtin_amdgcn_rcpf(x); }
__device__ __forceinline__ float fast_exp(float x) { return __expf(x); }
__device__ __forceinline__ float fast_sigmoid(float x) {
    return fast_rcp(1.0f + fast_exp(-x));
}

// 1 row/thread, fused accumulation.
// - L1+L2 (the ~2500-weight bulk) is a ROLLED k-loop: per-thread arrays are
//   only indexed by fully-unrolled j (stay in VGPRs); weights are uniform
//   runtime-k s_loads (<=~40 live SGPR scalars per iteration -> no SGPR
//   spill-to-VGPR-lane traffic, which inflated VALU issue 3.3x in rounds 2/4).
// - L3+L4 are FULLY UNROLLED: their bodies read h2[k]/h3[k], which must be
//   compile-time indexed to stay in VGPRs (rule #20); only ~670 weights.
__global__ __launch_bounds__(256)
__attribute__((amdgpu_waves_per_eu(4, 8)))
void sinkhorn_mlp_kernel(
    const float* __restrict__ margins,
    const float* __restrict__ W1, const float* __restrict__ b1,
    const float* __restrict__ W2, const float* __restrict__ b2,
    const float* __restrict__ W3, const float* __restrict__ b3,
    const float* __restrict__ W4, const float* __restrict__ b4,
    float* __restrict__ out_mus, float* __restrict__ out_V, int n)
{
    int r = blockIdx.x * blockDim.x + threadIdx.x;
    if (r >= n) return;

    // ---- load margins (6 floats, 8B-aligned) ----
    const float2* mp = reinterpret_cast<const float2*>(margins + (size_t)r * 6);
    float2 mv0 = mp[0], mv1 = mp[1], mv2 = mp[2];
    float m0 = mv0.x, m1 = mv0.y, m2 = mv1.x, m3 = mv1.y, m4 = mv2.x, m5 = mv2.y;

    // ---- layers 1+2 fused: h2[j] = b2[j] + sum_k relu(h1_k) * W2[k][j] ----
    float h2[32];
#pragma unroll
    for (int j = 0; j < 32; ++j) h2[j] = b2[j];

#pragma unroll 1
    for (int k = 0; k < 64; ++k) {
        float t = b1[k];
        t = fmaf(m0, W1[k],       t);
        t = fmaf(m1, W1[64 + k],  t);
        t = fmaf(m2, W1[128 + k], t);
        t = fmaf(m3, W1[192 + k], t);
        t = fmaf(m4, W1[256 + k], t);
        t = fmaf(m5, W1[320 + k], t);
        t = fmaxf(t, 0.0f);
        const float* w2r = W2 + k * 32;
#pragma unroll
        for (int j = 0; j < 32; ++j) h2[j] = fmaf(t, w2r[j], h2[j]);
    }

    // ---- layer 3 fused (FULLY unrolled: h2[k] must be compile-time) ----
    float h3[16];
#pragma unroll
    for (int j = 0; j < 16; ++j) h3[j] = b3[j];
#pragma unroll
    for (int k = 0; k < 32; ++k) {
        float t = fmaxf(h2[k], 0.0f);
#pragma unroll
        for (int j = 0; j < 16; ++j) h3[j] = fmaf(t, W3[k * 16 + j], h3[j]);
    }

    // ---- layer 4 fused (FULLY unrolled) ----
    float pars[9];
#pragma unroll
    for (int j = 0; j < 9; ++j) pars[j] = b4[j];
#pragma unroll
    for (int k = 0; k < 16; ++k) {
        float t = fmaxf(h3[k], 0.0f);
#pragma unroll
        for (int j = 0; j < 9; ++j) pars[j] = fmaf(t, W4[k * 9 + j], pars[j]);
    }

    // ---- heads ----
    float p0 = fast_exp(pars[0]);
    float p1 = fast_exp(pars[1]);
    float p2 = fast_exp(pars[2]);
    float p3 = fast_exp(pars[3]);

    float A00 = p3 * p0, A01 = p3 * p1, A02 = p3 * p2;
    float A10 = p3 * p1, A11 = p3 * p0, A12 = p3 * p1;
    float A20 = p3 * p2, A21 = p3 * p1, A22 = p3 * p0;

    float sm0 = fast_sigmoid(pars[4]);
    float sm1 = fast_sigmoid(pars[5]);
    float sf0 = fast_sigmoid(pars[6]);
    float sf1 = fast_sigmoid(pars[7]);
    float V   = fast_exp(pars[8]);

    float rc0 = m0 * sm0, rc1 = m1 * sm1, rc2 = m2;   // row targets
    float cc0 = m3 * sf0, cc1 = m4 * sf1, cc2 = m5;   // col targets
    float mum0_0 = m0 * (1.0f - sm0);
    float mum0_1 = m1 * (1.0f - sm1);
    float mu0f_0 = m3 * (1.0f - sf0);
    float mu0f_1 = m4 * (1.0f - sf1);

    // ---- Sinkhorn: 10 iterations (register-resident 3x3) ----
#pragma unroll
    for (int it = 0; it < 10; ++it) {
        float f0 = rc0 * fast_rcp(A00 + A01 + A02 + SEPS);
        float f1 = rc1 * fast_rcp(A10 + A11 + A12 + SEPS);
        float f2 = rc2 * fast_rcp(A20 + A21 + A22 + SEPS);
        A00 *= f0; A01 *= f0; A02 *= f0;
        A10 *= f1; A11 *= f1; A12 *= f1;
        A20 *= f2; A21 *= f2; A22 *= f2;
        float g0 = cc0 * fast_rcp(A00 + A10 + A20 + SEPS);
        float g1 = cc1 * fast_rcp(A01 + A11 + A21 + SEPS);
        float g2 = cc2 * fast_rcp(A02 + A12 + A22 + SEPS);
        A00 *= g0; A10 *= g0; A20 *= g0;
        A01 *= g1; A11 *= g1; A21 *= g1;
        A02 *= g2; A12 *= g2; A22 *= g2;
    }

    // ---- output: mus (4x4 row-major) then V ----
    float4* o = reinterpret_cast<float4*>(out_mus + (size_t)r * 16);
    o[0] = make_float4(A00, A01, A02, mum0_0);
    o[1] = make_float4(A10, A11, A12, mum0_1);
    o[2] = make_float4(A20, A21, A22, 0.0f);
    o[3] = make_float4(mu0f_0, mu0f_1, 0.0f, 0.0f);
    out_V[r] = V;
}

extern "C" void kernel_launch(void* const* d_in, const int* in_sizes, int n_in,
                              void* d_out, int out_size, void* d_ws, size_t ws_size,
                              hipStream_t stream) {
    const float* margins = (const float*)d_in[0];
    const float* W1 = (const float*)d_in[1];
    const float* b1 = (const float*)d_in[2];
    const float* W2 = (const float*)d_in[3];
    const float* b2 = (const float*)d_in[4];
    const float* W3 = (const float*)d_in[5];
    const float* b3 = (const float*)d_in[6];
    const float* W4 = (const float*)d_in[7];
    const float* b4 = (const float*)d_in[8];

    int n = in_sizes[0] / 6;
    float* out_mus = (float*)d_out;
    float* out_V   = out_mus + (size_t)n * 16;

    dim3 block(256);
    dim3 grid((n + 255) / 256);
    sinkhorn_mlp_kernel<<<grid, block, 0, stream>>>(
        margins, W1, b1, W2, b2, W3, b3, W4, b4, out_mus, out_V, n);
}

// Round 8
// 160.624 us; speedup vs baseline: 12.0341x; 1.0669x over previous
//
#include <hip/hip_runtime.h>

#define SEPS 1e-10f

typedef float v2f __attribute__((ext_vector_type(2)));

__device__ __forceinline__ float fast_rcp(float x) { return __builtin_amdgcn_rcpf(x); }
__device__ __forceinline__ float fast_exp(float x) { return __expf(x); }
__device__ __forceinline__ float fast_sigmoid(float x) {
    return fast_rcp(1.0f + fast_exp(-x));
}
__device__ __forceinline__ v2f splat2(float x) { v2f r; r.x = x; r.y = x; return r; }

// 1 row/thread, fused accumulation, L1+L2 k-loop ROLLED (round-7 win: keeps
// live uniform weights ~39 scalars -> no SGPR-spill VALU traffic).
// NEW: j-dimension packed as float2 -> v_pk_fma_f32 (VOP3P, gfx90a+):
// one issue slot = 2 fp32 FMAs. L2: 2048->1024 issues, L3: 512->256.
// L4 left scalar (row stride 9 floats breaks 8B alignment).
// If the backend declines to pack, each v2f op decays to 2 scalar ops
// (neutral vs round 7, not a regression).
__global__ __launch_bounds__(256)
__attribute__((amdgpu_waves_per_eu(4, 8)))
void sinkhorn_mlp_kernel(
    const float* __restrict__ margins,
    const float* __restrict__ W1, const float* __restrict__ b1,
    const float* __restrict__ W2, const float* __restrict__ b2,
    const float* __restrict__ W3, const float* __restrict__ b3,
    const float* __restrict__ W4, const float* __restrict__ b4,
    float* __restrict__ out_mus, float* __restrict__ out_V, int n)
{
    int r = blockIdx.x * blockDim.x + threadIdx.x;
    if (r >= n) return;

    // ---- load margins (6 floats, 8B-aligned) ----
    const float2* mp = reinterpret_cast<const float2*>(margins + (size_t)r * 6);
    float2 mv0 = mp[0], mv1 = mp[1], mv2 = mp[2];
    float m0 = mv0.x, m1 = mv0.y, m2 = mv1.x, m3 = mv1.y, m4 = mv2.x, m5 = mv2.y;

    // ---- layers 1+2 fused, j packed in pairs: h2p[jp] covers j=2jp,2jp+1 ----
    v2f h2p[16];
    const v2f* b2v = reinterpret_cast<const v2f*>(b2);
#pragma unroll
    for (int jp = 0; jp < 16; ++jp) h2p[jp] = b2v[jp];

#pragma unroll 1
    for (int k = 0; k < 64; ++k) {
        float t = b1[k];
        t = fmaf(m0, W1[k],       t);
        t = fmaf(m1, W1[64 + k],  t);
        t = fmaf(m2, W1[128 + k], t);
        t = fmaf(m3, W1[192 + k], t);
        t = fmaf(m4, W1[256 + k], t);
        t = fmaf(m5, W1[320 + k], t);
        t = fmaxf(t, 0.0f);
        v2f tv = splat2(t);
        const v2f* w2r = reinterpret_cast<const v2f*>(W2 + k * 32);
#pragma unroll
        for (int jp = 0; jp < 16; ++jp)
            h2p[jp] = __builtin_elementwise_fma(tv, w2r[jp], h2p[jp]);
    }

    // ---- layer 3 fused, packed (W3 rows: 16 floats, 8B-aligned) ----
    v2f h3p[8];
    const v2f* b3v = reinterpret_cast<const v2f*>(b3);
#pragma unroll
    for (int jp = 0; jp < 8; ++jp) h3p[jp] = b3v[jp];
#pragma unroll
    for (int k = 0; k < 32; ++k) {
        float hk = (k & 1) ? h2p[k >> 1].y : h2p[k >> 1].x;   // compile-time select
        float t = fmaxf(hk, 0.0f);
        v2f tv = splat2(t);
        const v2f* w3r = reinterpret_cast<const v2f*>(W3 + k * 16);
#pragma unroll
        for (int jp = 0; jp < 8; ++jp)
            h3p[jp] = __builtin_elementwise_fma(tv, w3r[jp], h3p[jp]);
    }

    // ---- layer 4 fused, scalar (row stride 9 floats -> unaligned pairs) ----
    float pars[9];
#pragma unroll
    for (int j = 0; j < 9; ++j) pars[j] = b4[j];
#pragma unroll
    for (int k = 0; k < 16; ++k) {
        float hk = (k & 1) ? h3p[k >> 1].y : h3p[k >> 1].x;
        float t = fmaxf(hk, 0.0f);
#pragma unroll
        for (int j = 0; j < 9; ++j) pars[j] = fmaf(t, W4[k * 9 + j], pars[j]);
    }

    // ---- heads ----
    float p0 = fast_exp(pars[0]);
    float p1 = fast_exp(pars[1]);
    float p2 = fast_exp(pars[2]);
    float p3 = fast_exp(pars[3]);

    float A00 = p3 * p0, A01 = p3 * p1, A02 = p3 * p2;
    float A10 = p3 * p1, A11 = p3 * p0, A12 = p3 * p1;
    float A20 = p3 * p2, A21 = p3 * p1, A22 = p3 * p0;

    float sm0 = fast_sigmoid(pars[4]);
    float sm1 = fast_sigmoid(pars[5]);
    float sf0 = fast_sigmoid(pars[6]);
    float sf1 = fast_sigmoid(pars[7]);
    float V   = fast_exp(pars[8]);

    float rc0 = m0 * sm0, rc1 = m1 * sm1, rc2 = m2;   // row targets
    float cc0 = m3 * sf0, cc1 = m4 * sf1, cc2 = m5;   // col targets
    float mum0_0 = m0 * (1.0f - sm0);
    float mum0_1 = m1 * (1.0f - sm1);
    float mu0f_0 = m3 * (1.0f - sf0);
    float mu0f_1 = m4 * (1.0f - sf1);

    // ---- Sinkhorn: 10 iterations (register-resident 3x3, scalar) ----
#pragma unroll
    for (int it = 0; it < 10; ++it) {
        float f0 = rc0 * fast_rcp(A00 + A01 + A02 + SEPS);
        float f1 = rc1 * fast_rcp(A10 + A11 + A12 + SEPS);
        float f2 = rc2 * fast_rcp(A20 + A21 + A22 + SEPS);
        A00 *= f0; A01 *= f0; A02 *= f0;
        A10 *= f1; A11 *= f1; A12 *= f1;
        A20 *= f2; A21 *= f2; A22 *= f2;
        float g0 = cc0 * fast_rcp(A00 + A10 + A20 + SEPS);
        float g1 = cc1 * fast_rcp(A01 + A11 + A21 + SEPS);
        float g2 = cc2 * fast_rcp(A02 + A12 + A22 + SEPS);
        A00 *= g0; A10 *= g0; A20 *= g0;
        A01 *= g1; A11 *= g1; A21 *= g1;
        A02 *= g2; A12 *= g2; A22 *= g2;
    }

    // ---- output: mus (4x4 row-major) then V ----
    float4* o = reinterpret_cast<float4*>(out_mus + (size_t)r * 16);
    o[0] = make_float4(A00, A01, A02, mum0_0);
    o[1] = make_float4(A10, A11, A12, mum0_1);
    o[2] = make_float4(A20, A21, A22, 0.0f);
    o[3] = make_float4(mu0f_0, mu0f_1, 0.0f, 0.0f);
    out_V[r] = V;
}

extern "C" void kernel_launch(void* const* d_in, const int* in_sizes, int n_in,
                              void* d_out, int out_size, void* d_ws, size_t ws_size,
                              hipStream_t stream) {
    const float* margins = (const float*)d_in[0];
    const float* W1 = (const float*)d_in[1];
    const float* b1 = (const float*)d_in[2];
    const float* W2 = (const float*)d_in[3];
    const float* b2 = (const float*)d_in[4];
    const float* W3 = (const float*)d_in[5];
    const float* b3 = (const float*)d_in[6];
    const float* W4 = (const float*)d_in[7];
    const float* b4 = (const float*)d_in[8];

    int n = in_sizes[0] / 6;
    float* out_mus = (float*)d_out;
    float* out_V   = out_mus + (size_t)n * 16;

    dim3 block(256);
    dim3 grid((n + 255) / 256);
    sinkhorn_mlp_kernel<<<grid, block, 0, stream>>>(
        margins, W1, b1, W2, b2, W3, b3, W4, b4, out_mus, out_V, n);
}